// Round 1
// baseline (534.454 us; speedup 1.0000x reference)
//
#include <hip/hip_runtime.h>

// Problem constants
#define T_TOK 2048
#define HID   2048
#define IMID  768
#define NEXP  16
#define TOPK  2

#define NPAIR (T_TOK * TOPK)   // 4096
#define SLACK 64
#define NSLOT (NPAIR + SLACK)  // 4160 bucket slots incl. tile slack

#define BM 64
#define BK 32
#define LDSS 40  // 32 + 8 shorts pad: rows land 2-way on banks (free), keeps 16B align

typedef __attribute__((ext_vector_type(8))) short short8;
typedef __attribute__((ext_vector_type(4))) float floatx4;

__device__ __forceinline__ short f2bf(float f) {
    union { float f; unsigned u; } v; v.f = f;
    unsigned r = (v.u + 0x7FFFu + ((v.u >> 16) & 1u)) >> 16;  // RNE, inputs are finite
    return (short)r;
}

__device__ __forceinline__ void load_cvt8(const float* __restrict__ p, short* dst) {
    float4 x = *(const float4*)p;
    float4 y = *(const float4*)(p + 4);
    short8 v;
    v[0] = f2bf(x.x); v[1] = f2bf(x.y); v[2] = f2bf(x.z); v[3] = f2bf(x.w);
    v[4] = f2bf(y.x); v[5] = f2bf(y.y); v[6] = f2bf(y.z); v[7] = f2bf(y.w);
    *(short8*)dst = v;
}

// ---------------- routing ----------------
__global__ void k_count(const int* __restrict__ idx, int* __restrict__ counts) {
    int i = blockIdx.x * blockDim.x + threadIdx.x;
    if (i < NPAIR) atomicAdd(&counts[idx[i]], 1);
}

__global__ void k_scan(const int* __restrict__ counts, int* __restrict__ base,
                       int* __restrict__ cursor) {
    int s = 0;
    for (int e = 0; e < NEXP; e++) { base[e] = s; cursor[e] = s; s += counts[e]; }
}

__global__ void k_scatter(const int* __restrict__ idx, const float* __restrict__ w,
                          int* __restrict__ cursor, int* __restrict__ tok,
                          float* __restrict__ wgt) {
    int i = blockIdx.x * blockDim.x + threadIdx.x;
    if (i < NPAIR) {
        int e = idx[i];
        int p = atomicAdd(&cursor[e], 1);
        tok[p] = i / TOPK;
        wgt[p] = w[i];
    }
}

// ---------------- GEMM1: X_e @ gate_up^T -> SwiGLU -> mid (bf16) ----------------
// grid: (12 col-tiles of 64 over I=768, 64 row-tiles, 16 experts), block 256
__global__ __launch_bounds__(256) void k_gemm1(
    const float* __restrict__ hs, const float* __restrict__ gup,
    const int* __restrict__ counts, const int* __restrict__ base,
    const int* __restrict__ tok, short* __restrict__ mid)
{
    const int e = blockIdx.z, rt = blockIdx.y, ct = blockIdx.x;
    const int n = counts[e];
    if (rt * BM >= n) return;
    const int rowbase = base[e] + rt * BM;

    __shared__ short sA[BM][LDSS];
    __shared__ short sBg[BM][LDSS];
    __shared__ short sBu[BM][LDSS];
    __shared__ int s_tok[BM];

    const int tid = threadIdx.x;
    if (tid < BM) s_tok[tid] = tok[rowbase + tid];
    __syncthreads();

    const int lrow = tid >> 2;          // 0..63
    const int cg   = (tid & 3) * 8;     // 0,8,16,24

    const float* aptr = hs + (size_t)s_tok[lrow] * HID + cg;
    const float* gptr = gup + (size_t)e * (2 * IMID) * HID + (size_t)(ct * 64 + lrow) * HID + cg;
    const float* uptr = gptr + (size_t)IMID * HID;

    const int wave = tid >> 6;
    const int lane = tid & 63;
    const int m16  = lane & 15;
    const int quad = lane >> 4;

    floatx4 accg[4], accu[4];
#pragma unroll
    for (int i = 0; i < 4; i++) { accg[i] = (floatx4)0.0f; accu[i] = (floatx4)0.0f; }

    for (int k0 = 0; k0 < HID; k0 += BK) {
        load_cvt8(aptr + k0, &sA[lrow][cg]);
        load_cvt8(gptr + k0, &sBg[lrow][cg]);
        load_cvt8(uptr + k0, &sBu[lrow][cg]);
        __syncthreads();
        short8 af = *(const short8*)&sA[wave * 16 + m16][quad * 8];
#pragma unroll
        for (int cf = 0; cf < 4; cf++) {
            short8 bg = *(const short8*)&sBg[cf * 16 + m16][quad * 8];
            short8 bu = *(const short8*)&sBu[cf * 16 + m16][quad * 8];
            accg[cf] = __builtin_amdgcn_mfma_f32_16x16x32_bf16(af, bg, accg[cf], 0, 0, 0);
            accu[cf] = __builtin_amdgcn_mfma_f32_16x16x32_bf16(af, bu, accu[cf], 0, 0, 0);
        }
        __syncthreads();
    }

    const int nvalid = n - rt * BM;
#pragma unroll
    for (int cf = 0; cf < 4; cf++) {
#pragma unroll
        for (int r = 0; r < 4; r++) {
            int row = wave * 16 + quad * 4 + r;  // C/D layout: col=lane&15, row=quad*4+reg
            if (row < nvalid) {
                float g = accg[cf][r], u = accu[cf][r];
                float mval = g / (1.0f + __expf(-g)) * u;  // silu(g)*u
                mid[(size_t)(rowbase + row) * IMID + ct * 64 + cf * 16 + m16] = f2bf(mval);
            }
        }
    }
}

// ---------------- GEMM2: mid @ down^T * w -> scatter-add into out ----------------
// grid: (32 col-tiles of 64 over H=2048, 64 row-tiles, 16 experts), block 256
__global__ __launch_bounds__(256) void k_gemm2(
    const float* __restrict__ down, const short* __restrict__ mid,
    const int* __restrict__ counts, const int* __restrict__ base,
    const int* __restrict__ tok, const float* __restrict__ wgt,
    float* __restrict__ out)
{
    const int e = blockIdx.z, rt = blockIdx.y, ht = blockIdx.x;
    const int n = counts[e];
    if (rt * BM >= n) return;
    const int rowbase = base[e] + rt * BM;

    __shared__ short sA[BM][LDSS];
    __shared__ short sB[BM][LDSS];
    __shared__ int   s_tok[BM];
    __shared__ float s_w[BM];

    const int tid = threadIdx.x;
    if (tid < BM) { s_tok[tid] = tok[rowbase + tid]; s_w[tid] = wgt[rowbase + tid]; }

    const int lrow = tid >> 2;
    const int cg   = (tid & 3) * 8;

    const short* aptr = mid + (size_t)(rowbase + lrow) * IMID + cg;
    const float* bptr = down + (size_t)e * HID * IMID + (size_t)(ht * 64 + lrow) * IMID + cg;

    const int wave = tid >> 6;
    const int lane = tid & 63;
    const int m16  = lane & 15;
    const int quad = lane >> 4;

    floatx4 acc[4];
#pragma unroll
    for (int i = 0; i < 4; i++) acc[i] = (floatx4)0.0f;

    for (int k0 = 0; k0 < IMID; k0 += BK) {
        *(short8*)&sA[lrow][cg] = *(const short8*)(aptr + k0);  // already bf16
        load_cvt8(bptr + k0, &sB[lrow][cg]);
        __syncthreads();
        short8 af = *(const short8*)&sA[wave * 16 + m16][quad * 8];
#pragma unroll
        for (int cf = 0; cf < 4; cf++) {
            short8 bf_ = *(const short8*)&sB[cf * 16 + m16][quad * 8];
            acc[cf] = __builtin_amdgcn_mfma_f32_16x16x32_bf16(af, bf_, acc[cf], 0, 0, 0);
        }
        __syncthreads();
    }

    const int nvalid = n - rt * BM;
#pragma unroll
    for (int cf = 0; cf < 4; cf++) {
#pragma unroll
        for (int r = 0; r < 4; r++) {
            int row = wave * 16 + quad * 4 + r;
            if (row < nvalid) {
                int t = s_tok[row];
                float w = s_w[row];
                atomicAdd(&out[(size_t)t * HID + ht * 64 + cf * 16 + m16], w * acc[cf][r]);
            }
        }
    }
}

// ---------------- launch ----------------
extern "C" void kernel_launch(void* const* d_in, const int* in_sizes, int n_in,
                              void* d_out, int out_size, void* d_ws, size_t ws_size,
                              hipStream_t stream) {
    const float* hs   = (const float*)d_in[0];
    const int*   idx  = (const int*)d_in[1];
    const float* tkw  = (const float*)d_in[2];
    const float* gup  = (const float*)d_in[3];
    const float* down = (const float*)d_in[4];
    float* out = (float*)d_out;

    char* ws = (char*)d_ws;
    // ws layout: [counts 64B][base 64B][cursor 64B][pad][tok 4160*4][wgt 4160*4][pad][mid 4160*768*2]
    int*   counts = (int*)(ws + 0);
    int*   base   = (int*)(ws + 64);
    int*   cursor = (int*)(ws + 128);
    int*   tok    = (int*)(ws + 256);
    float* wgt    = (float*)(ws + 256 + NSLOT * 4);
    short* mid    = (short*)(ws + 33792);

    hipMemsetAsync(ws, 0, 33792, stream);                                   // counts/cursor/tok/wgt = 0
    hipMemsetAsync(d_out, 0, (size_t)T_TOK * HID * sizeof(float), stream);  // out accumulates via atomics

    k_count  <<<(NPAIR + 255) / 256, 256, 0, stream>>>(idx, counts);
    k_scan   <<<1, 1, 0, stream>>>(counts, base, cursor);
    k_scatter<<<(NPAIR + 255) / 256, 256, 0, stream>>>(idx, tkw, cursor, tok, wgt);
    k_gemm1  <<<dim3(IMID / 64, NPAIR / BM, NEXP), 256, 0, stream>>>(hs, gup, counts, base, tok, mid);
    k_gemm2  <<<dim3(HID / 64, NPAIR / BM, NEXP), 256, 0, stream>>>(down, mid, counts, base, tok, wgt, out);
}

// Round 2
// 443.071 us; speedup vs baseline: 1.2063x; 1.2063x over previous
//
#include <hip/hip_runtime.h>

#define TTOK  2048
#define HID   2048
#define IMID  768
#define NEXP  16
#define NPAIR 4096
#define NSLOT 4224          // 4096 + 128 slack
#define BM    128
#define BK    64
#define MAXT  48            // max tiles: 15 + 4096/128 = 47
#define LDB   72            // sB row stride in shorts (64 + 8 pad)
#define ABUF  (128 * 64)    // one A buffer, shorts

typedef __attribute__((ext_vector_type(8))) short  short8;
typedef __attribute__((ext_vector_type(4))) float  floatx4;
typedef __attribute__((ext_vector_type(2))) unsigned uint2v;

__device__ __forceinline__ unsigned pk2(float a, float b) {
    union { float f; unsigned u; } x{a}, y{b};
    unsigned ra = (x.u + 0x7FFFu + ((x.u >> 16) & 1u)) >> 16;
    unsigned rb = (y.u + 0x7FFFu + ((y.u >> 16) & 1u)) & 0xFFFF0000u;
    return ra | rb;
}

__device__ __forceinline__ short f2bf(float f) {
    union { float f; unsigned u; } v; v.f = f;
    return (short)((v.u + 0x7FFFu + ((v.u >> 16) & 1u)) >> 16);
}

__device__ __forceinline__ short8 cvt8(float4 a, float4 b) {
    union { unsigned u[4]; short8 s; } r;
    r.u[0] = pk2(a.x, a.y); r.u[1] = pk2(a.z, a.w);
    r.u[2] = pk2(b.x, b.y); r.u[3] = pk2(b.z, b.w);
    return r.s;
}

__device__ __forceinline__ void async_cp16(const void* g, void* l) {
    __builtin_amdgcn_global_load_lds(
        (const __attribute__((address_space(1))) void*)g,
        (__attribute__((address_space(3))) void*)l, 16, 0, 0);
}

// ---------- fused routing (block 0) + hs->bf16 convert (blocks 1..2048) ----------
__global__ __launch_bounds__(256) void k_pre(
    const float* __restrict__ hs, const int* __restrict__ idx,
    const float* __restrict__ tkw, int* __restrict__ ntiles,
    int4* __restrict__ tiles, int* __restrict__ tok,
    float* __restrict__ wgt, short* __restrict__ X)
{
    const int tid = threadIdx.x;
    if (blockIdx.x == 0) {
        __shared__ int cnt[NEXP], cur[NEXP];
        if (tid < NEXP) cnt[tid] = 0;
        __syncthreads();
        for (int i = tid; i < NPAIR; i += 256) atomicAdd(&cnt[idx[i]], 1);
        __syncthreads();
        if (tid == 0) {
            int s = 0, nt = 0;
            for (int e = 0; e < NEXP; e++) {
                cur[e] = s;
                int n = cnt[e];
                for (int tt = 0; tt * BM < n; tt++) {
                    tiles[nt] = make_int4(e, s + tt * BM, min(BM, n - tt * BM), 0);
                    nt++;
                }
                s += n;
            }
            *ntiles = nt;
        }
        __syncthreads();
        for (int i = tid; i < NPAIR; i += 256) {
            int e = idx[i];
            int p = atomicAdd(&cur[e], 1);
            tok[p] = i >> 1;
            wgt[p] = tkw[i];
        }
        for (int i = NPAIR + tid; i < NSLOT; i += 256) { tok[i] = 0; wgt[i] = 0.0f; }
    } else {
        const int row = blockIdx.x - 1;
        const float* src = hs + (size_t)row * HID + tid * 8;
        float4 a = *(const float4*)src;
        float4 b = *(const float4*)(src + 4);
        *(short8*)(X + (size_t)row * HID + tid * 8) = cvt8(a, b);
    }
}

// ---------- GEMM1: X[tok] @ gate_up^T -> silu(g)*u*w -> mid (bf16) ----------
// grid (12 ct over I, MAXT tiles), block 256
__global__ __launch_bounds__(256, 2) void k_gemm1(
    const float* __restrict__ gup, const short* __restrict__ X,
    const int* __restrict__ ntiles, const int4* __restrict__ tiles,
    const int* __restrict__ tok, const float* __restrict__ wgt,
    short* __restrict__ mid)
{
    if ((int)blockIdx.y >= *ntiles) return;
    const int4 td = tiles[blockIdx.y];
    const int e = td.x, rowstart = td.y, nvalid = td.z;
    const int ct = blockIdx.x;

    __shared__ short sA[2 * ABUF];
    __shared__ short sB[128 * LDB];
    __shared__ int   s_tok[BM];
    __shared__ float s_w[BM];

    const int tid = threadIdx.x;
    if (tid < BM) { s_tok[tid] = tok[rowstart + tid]; s_w[tid] = wgt[rowstart + tid]; }
    __syncthreads();

    const int wave = tid >> 6, lane = tid & 63;
    const int m16 = lane & 15, quad = lane >> 4;

    // A async-copy params (XOR swizzle groups of 8 bf16)
    const int lrow = tid >> 3;                 // 0..31
    const int gsw  = (tid & 7) ^ (lrow & 7);
    const short* aga[4];
#pragma unroll
    for (int j = 0; j < 4; j++)
        aga[j] = X + (size_t)s_tok[lrow + j * 32] * HID + gsw * 8;

    // B staging params (contiguous per-instr coalescing)
    const int colgrp = tid & 15;               // float4 index within 64-f32 row
    const int rowoff = tid >> 4;               // 0..15
    const float* bgate = gup + ((size_t)e * (2 * IMID) + ct * 64) * HID;
    const float* bup   = bgate + (size_t)IMID * HID;

    float4 br[8];
    auto loadB = [&](int k0) {
#pragma unroll
        for (int i = 0; i < 8; i++) {
            int brow = i * 16 + rowoff;
            const float* p = (i < 4) ? (bgate + (size_t)brow * HID)
                                     : (bup + (size_t)(brow - 64) * HID);
            br[i] = *(const float4*)(p + k0 + colgrp * 4);
        }
    };
    auto issueA = [&](int k0, short* dst) {
#pragma unroll
        for (int j = 0; j < 4; j++)
            async_cp16(aga[j] + k0, dst + j * 2048 + wave * 512);
    };

    const int Wm = (wave >> 1) << 6;   // 0 / 64
    const int Wi = (wave & 1) << 5;    // 0 / 32
    floatx4 ag[4][2], au[4][2];
#pragma unroll
    for (int a = 0; a < 4; a++)
#pragma unroll
        for (int b = 0; b < 2; b++) { ag[a][b] = (floatx4)0.0f; au[a][b] = (floatx4)0.0f; }

    loadB(0);
    issueA(0, sA);

    const int nsteps = HID / BK;  // 32
    for (int ks = 0; ks < nsteps; ks++) {
        short* Acur  = sA + (ks & 1) * ABUF;
        short* Anext = sA + ((ks + 1) & 1) * ABUF;

        // convert current B regs -> LDS
#pragma unroll
        for (int i = 0; i < 8; i++) {
            int brow = i * 16 + rowoff;
            uint2v w2;
            w2.x = pk2(br[i].x, br[i].y);
            w2.y = pk2(br[i].z, br[i].w);
            *(uint2v*)&sB[brow * LDB + colgrp * 4] = w2;
        }
        __syncthreads();

        if (ks + 1 < nsteps) {
            issueA((ks + 1) * BK, Anext);
            loadB((ks + 1) * BK);
        }

        // MFMA phase
#pragma unroll
        for (int h = 0; h < 2; h++) {
            short8 af[4];
#pragma unroll
            for (int mf = 0; mf < 4; mf++) {
                int row = Wm + mf * 16 + m16;
                int gc = (h * 4 + quad) ^ (row & 7);
                af[mf] = *(const short8*)&Acur[row * 64 + gc * 8];
            }
#pragma unroll
            for (int nf = 0; nf < 2; nf++) {
                const short8 bg = *(const short8*)&sB[(Wi + nf * 16 + m16) * LDB + h * 32 + quad * 8];
                const short8 bu = *(const short8*)&sB[(64 + Wi + nf * 16 + m16) * LDB + h * 32 + quad * 8];
#pragma unroll
                for (int mf = 0; mf < 4; mf++) {
                    ag[mf][nf] = __builtin_amdgcn_mfma_f32_16x16x32_bf16(af[mf], bg, ag[mf][nf], 0, 0, 0);
                    au[mf][nf] = __builtin_amdgcn_mfma_f32_16x16x32_bf16(af[mf], bu, au[mf][nf], 0, 0, 0);
                }
            }
        }
        __syncthreads();
    }

    // epilogue: SwiGLU * router weight -> mid (bf16)
#pragma unroll
    for (int mf = 0; mf < 4; mf++) {
#pragma unroll
        for (int r = 0; r < 4; r++) {
            int m = Wm + mf * 16 + quad * 4 + r;
            if (m < nvalid) {
                float w = s_w[m];
                size_t rowp = (size_t)(rowstart + m) * IMID + ct * 64;
#pragma unroll
                for (int nf = 0; nf < 2; nf++) {
                    float g = ag[mf][nf][r], u = au[mf][nf][r];
                    float val = g / (1.0f + __expf(-g)) * u * w;
                    mid[rowp + Wi + nf * 16 + m16] = f2bf(val);
                }
            }
        }
    }
}

// ---------- GEMM2: mid @ down^T -> atomicAdd into out ----------
// grid (16 ct over H, MAXT tiles), block 256
__global__ __launch_bounds__(256, 2) void k_gemm2(
    const float* __restrict__ down, const short* __restrict__ mid,
    const int* __restrict__ ntiles, const int4* __restrict__ tiles,
    const int* __restrict__ tok, float* __restrict__ out)
{
    if ((int)blockIdx.y >= *ntiles) return;
    const int4 td = tiles[blockIdx.y];
    const int e = td.x, rowstart = td.y, nvalid = td.z;
    const int ct = blockIdx.x;

    __shared__ short sA[2 * ABUF];
    __shared__ short sB[128 * LDB];
    __shared__ int   s_tok[BM];

    const int tid = threadIdx.x;
    if (tid < BM) s_tok[tid] = tok[rowstart + tid];
    __syncthreads();

    const int wave = tid >> 6, lane = tid & 63;
    const int m16 = lane & 15, quad = lane >> 4;

    const int lrow = tid >> 3;
    const int gsw  = (tid & 7) ^ (lrow & 7);
    const short* aga[4];
#pragma unroll
    for (int j = 0; j < 4; j++)
        aga[j] = mid + (size_t)(rowstart + lrow + j * 32) * IMID + gsw * 8;

    const int colgrp = tid & 15;
    const int rowoff = tid >> 4;
    const float* bbase = down + ((size_t)e * HID + ct * 128) * IMID;

    float4 br[8];
    auto loadB = [&](int k0) {
#pragma unroll
        for (int i = 0; i < 8; i++)
            br[i] = *(const float4*)(bbase + (size_t)(i * 16 + rowoff) * IMID + k0 + colgrp * 4);
    };
    auto issueA = [&](int k0, short* dst) {
#pragma unroll
        for (int j = 0; j < 4; j++)
            async_cp16(aga[j] + k0, dst + j * 2048 + wave * 512);
    };

    const int Wm = (wave >> 1) << 6;
    const int Wn = (wave & 1) << 6;   // 0 / 64 over the 128 H-cols
    floatx4 acc[4][4];
#pragma unroll
    for (int a = 0; a < 4; a++)
#pragma unroll
        for (int b = 0; b < 4; b++) acc[a][b] = (floatx4)0.0f;

    loadB(0);
    issueA(0, sA);

    const int nsteps = IMID / BK;  // 12
    for (int ks = 0; ks < nsteps; ks++) {
        short* Acur  = sA + (ks & 1) * ABUF;
        short* Anext = sA + ((ks + 1) & 1) * ABUF;

#pragma unroll
        for (int i = 0; i < 8; i++) {
            int brow = i * 16 + rowoff;
            uint2v w2;
            w2.x = pk2(br[i].x, br[i].y);
            w2.y = pk2(br[i].z, br[i].w);
            *(uint2v*)&sB[brow * LDB + colgrp * 4] = w2;
        }
        __syncthreads();

        if (ks + 1 < nsteps) {
            issueA((ks + 1) * BK, Anext);
            loadB((ks + 1) * BK);
        }

#pragma unroll
        for (int h = 0; h < 2; h++) {
            short8 af[4];
#pragma unroll
            for (int mf = 0; mf < 4; mf++) {
                int row = Wm + mf * 16 + m16;
                int gc = (h * 4 + quad) ^ (row & 7);
                af[mf] = *(const short8*)&Acur[row * 64 + gc * 8];
            }
#pragma unroll
            for (int nf = 0; nf < 4; nf++) {
                const short8 bf_ = *(const short8*)&sB[(Wn + nf * 16 + m16) * LDB + h * 32 + quad * 8];
#pragma unroll
                for (int mf = 0; mf < 4; mf++)
                    acc[mf][nf] = __builtin_amdgcn_mfma_f32_16x16x32_bf16(af[mf], bf_, acc[mf][nf], 0, 0, 0);
            }
        }
        __syncthreads();
    }

#pragma unroll
    for (int mf = 0; mf < 4; mf++) {
#pragma unroll
        for (int r = 0; r < 4; r++) {
            int m = Wm + mf * 16 + quad * 4 + r;
            if (m < nvalid) {
                int t = s_tok[m];
                float* op = out + (size_t)t * HID + ct * 128;
#pragma unroll
                for (int nf = 0; nf < 4; nf++)
                    atomicAdd(op + Wn + nf * 16 + m16, acc[mf][nf][r]);
            }
        }
    }
}

// ---------- launch ----------
extern "C" void kernel_launch(void* const* d_in, const int* in_sizes, int n_in,
                              void* d_out, int out_size, void* d_ws, size_t ws_size,
                              hipStream_t stream) {
    const float* hs   = (const float*)d_in[0];
    const int*   idx  = (const int*)d_in[1];
    const float* tkw  = (const float*)d_in[2];
    const float* gup  = (const float*)d_in[3];
    const float* down = (const float*)d_in[4];
    float* out = (float*)d_out;

    char* ws = (char*)d_ws;
    int*   ntiles = (int*)ws;
    int4*  tiles  = (int4*)(ws + 16);
    int*   tok    = (int*)(ws + 1024);
    float* wgt    = (float*)(ws + 1024 + NSLOT * 4);
    short* mid    = (short*)(ws + 36864);
    short* X      = (short*)(ws + 36864 + (size_t)NSLOT * IMID * 2);

    hipMemsetAsync(d_out, 0, (size_t)TTOK * HID * sizeof(float), stream);
    k_pre  <<<2049, 256, 0, stream>>>(hs, idx, tkw, ntiles, tiles, tok, wgt, X);
    k_gemm1<<<dim3(IMID / 64, MAXT), 256, 0, stream>>>(gup, X, ntiles, tiles, tok, wgt, mid);
    k_gemm2<<<dim3(HID / 128, MAXT), 256, 0, stream>>>(down, mid, ntiles, tiles, tok, out);
}